// Round 7
// baseline (368.706 us; speedup 1.0000x reference)
//
#include <hip/hip_runtime.h>
#include <hip/hip_bf16.h>

#define BB 4
#define CMv 256
#define CTv 64
#define CAv 128
#define NTOK 6400
/* 128^-0.5 * log2(e): softmax runs in exp2 domain */
#define QSCL 0.12753102198064644f

typedef unsigned short u16;
typedef __attribute__((ext_vector_type(8))) short sh8;     // 8 bf16
typedef __attribute__((ext_vector_type(4))) float f32x4;
typedef __attribute__((ext_vector_type(16))) float f32x16;
typedef __attribute__((ext_vector_type(4))) unsigned uint4v;
typedef __attribute__((ext_vector_type(2))) unsigned uint2v;

__device__ __forceinline__ u16 f2bf(float f) {
  return __builtin_bit_cast(u16, __float2bfloat16(f));
}
__device__ __forceinline__ float bf2f(u16 x) {
  unsigned u = ((unsigned)x) << 16;
  return __builtin_bit_cast(float, u);
}
__device__ __forceinline__ unsigned pk2(float a, float b) {
  return ((unsigned)f2bf(b) << 16) | (unsigned)f2bf(a);
}
__device__ __forceinline__ f32x16 zero16() {
  f32x16 z;
#pragma unroll
  for (int i = 0; i < 16; i++) z[i] = 0.f;
  return z;
}
typedef const __attribute__((address_space(1))) unsigned int* gas_p;
typedef __attribute__((address_space(3))) unsigned int* las_p;
__device__ __forceinline__ void gl_lds16(const u16* g, u16* l) {
  __builtin_amdgcn_global_load_lds((gas_p)g, (las_p)l, 16, 0, 0);
}

// ---------------- weight transpose prep ----------------
__global__ __launch_bounds__(256) void prepw(const float* __restrict__ wq,
                                             const float* __restrict__ wk,
                                             const float* __restrict__ wv,
                                             const float* __restrict__ wo,
                                             float* __restrict__ wqT,
                                             float* __restrict__ wkT,
                                             float* __restrict__ wvT,
                                             float* __restrict__ woT) {
  int i0 = blockIdx.x * 256 + threadIdx.x;
  for (int idx = i0; idx < 256 * 128; idx += 32 * 256) {
    int ch = idx & 127, cin = idx >> 7;
    wqT[idx] = wq[ch * CMv + cin];
  }
  for (int idx = i0; idx < 64 * 128; idx += 32 * 256) {
    int ch = idx & 127, cin = idx >> 7;
    wkT[idx] = wk[ch * CTv + cin];
    wvT[idx] = wv[ch * CTv + cin];
  }
  for (int idx = i0; idx < 128 * 256; idx += 32 * 256) {
    int ch = idx & 255, c = idx >> 8;
    woT[idx] = wo[ch * CAv + c];
  }
}

// ---------------- Q projection (scale+log2e folded) ----------------
__global__ __launch_bounds__(256) void qproj(const float* __restrict__ met,
                                             const float* __restrict__ wqT,
                                             const float* __restrict__ bq,
                                             u16* __restrict__ Qtm) {
  const int b = blockIdx.x / 100;
  const int tokb = (blockIdx.x % 100) * 64;
  const int tok = threadIdx.x & 63;
  const int chg = __builtin_amdgcn_readfirstlane(threadIdx.x >> 6);  // 0..3
  const float* wt = wqT + chg * 32;
  const float* mp = met + (size_t)b * CMv * NTOK + tokb + tok;
  float acc[32];
#pragma unroll
  for (int j = 0; j < 32; j++) acc[j] = bq[chg * 32 + j];
#pragma unroll 8
  for (int cin = 0; cin < CMv; cin++) {
    float x = mp[(size_t)cin * NTOK];
#pragma unroll
    for (int j = 0; j < 32; j++) acc[j] = fmaf(wt[cin * CAv + j], x, acc[j]);
  }
  u16* qp = Qtm + ((size_t)b * NTOK + tokb + tok) * CAv + chg * 32;
#pragma unroll
  for (int v = 0; v < 4; v++) {
    sh8 pkv;
#pragma unroll
    for (int e = 0; e < 8; e++) pkv[e] = (short)f2bf(acc[v * 8 + e] * QSCL);
    *(sh8*)(qp + v * 8) = pkv;
  }
}

// ---------------- K,V projections ----------------
__global__ __launch_bounds__(512) void kvproj(const float* __restrict__ ter,
                                              const float* __restrict__ wkT,
                                              const float* __restrict__ bk,
                                              const float* __restrict__ wvT,
                                              const float* __restrict__ bv,
                                              u16* __restrict__ Ktm,
                                              u16* __restrict__ Vcm) {
  const int b = blockIdx.x / 100;
  const int tokb = (blockIdx.x % 100) * 64;
  const int tok = threadIdx.x & 63;
  const int grp = __builtin_amdgcn_readfirstlane(threadIdx.x >> 6);  // 0..7
  const bool isV = grp >= 4;
  const int chg = isV ? (grp - 4) : grp;
  const float* wt = (isV ? wvT : wkT) + chg * 32;
  const float* bias = isV ? bv : bk;
  const float* tp = ter + (size_t)b * CTv * NTOK + tokb + tok;
  float acc[32];
#pragma unroll
  for (int j = 0; j < 32; j++) acc[j] = bias[chg * 32 + j];
#pragma unroll 8
  for (int cin = 0; cin < CTv; cin++) {
    float x = tp[(size_t)cin * NTOK];
#pragma unroll
    for (int j = 0; j < 32; j++) acc[j] = fmaf(wt[cin * CAv + j], x, acc[j]);
  }
  if (!isV) {
    u16* kp = Ktm + ((size_t)b * NTOK + tokb + tok) * CAv + chg * 32;
#pragma unroll
    for (int v = 0; v < 4; v++) {
      sh8 pkv;
#pragma unroll
      for (int e = 0; e < 8; e++) pkv[e] = (short)f2bf(acc[v * 8 + e]);
      *(sh8*)(kp + v * 8) = pkv;
    }
  } else {
    u16* vp = Vcm + ((size_t)b * CAv + chg * 32) * NTOK + tokb + tok;
#pragma unroll
    for (int j = 0; j < 32; j++) vp[(size_t)j * NTOK] = f2bf(acc[j]);
  }
}

// ---------------- flash attention ----------------
// Grid 400 = 25 q-tiles x 16 groups (g = b*4 + kvq); blockIdx = qt*16 + g so a
// (b,kvq) group's K/V quarter pins to XCD g%8. Block: 8 waves x 32 q-rows
// (Q_T=256) -- each staged K/V byte serves 256 q-rows (2x R6). Waves share each
// 32-kv K/V tile in LDS (triple-buffered, staged 2 ahead via global_load_lds;
// counted vmcnt(2) + one raw s_barrier per tile -- queue never drains).
// K XOR key l31&15 (16 slots, phase-minimal); V key (c>>1)&3 (already minimal).
// Partial O (unnormalized bf16) + m/l per kv-quarter; merged in outproj.
__global__ __launch_bounds__(512, 4) void attn(const u16* __restrict__ Qtm,
                                               const u16* __restrict__ Ktm,
                                               const u16* __restrict__ Vcm,
                                               u16* __restrict__ Opart,
                                               float* __restrict__ Mpart,
                                               float* __restrict__ Lpart) {
  __shared__ __align__(16) unsigned char smem[49152];  // 3 x (K 8KB | V 8KB)

  const int tid = threadIdx.x;
  const int w = tid >> 6;        // q-subtile 0..7
  const int lane = tid & 63;
  const int l31 = lane & 31;
  const int h = lane >> 5;

  const int g = blockIdx.x & 15;
  const int qt = blockIdx.x >> 4;      // 0..24
  const int b = g >> 2;
  const int kvq = g & 3;
  const int qb0 = qt * 256;
  const int kv00 = kvq * 1600;

  const u16* Qb = Qtm + ((size_t)b * NTOK + qb0 + w * 32 + l31) * CAv;
  const u16* Kb = Ktm + (size_t)b * NTOK * CAv;
  const u16* Vb = Vcm + (size_t)b * CAv * NTOK;

  // Q fragments (B-operand): col=q=l31, k = kk*16 + 8h + j
  sh8 qf[8];
#pragma unroll
  for (int kk = 0; kk < 8; kk++) qf[kk] = *(const sh8*)(Qb + kk * 16 + h * 8);

  // K DMA source (1 inst/wave, 4 rows x 256B): row kr = w*4 + (lane>>4),
  // LDS slot = lane&15, source chunk = (lane&15) ^ (kr&15)
  const int kr = w * 4 + (lane >> 4);
  const u16* ksrc = Kb + ((size_t)kv00 + kr) * CAv + (((lane & 15) ^ (kr & 15)) * 8);
  // V DMA source (1 inst/wave, 16 rows x 64B): c = w*16 + (lane>>2),
  // slot = lane&3, chunk = (lane&3) ^ ((c>>1)&3) = (lane&3) ^ ((lane>>3)&3)
  const int vc = w * 16 + (lane >> 2);
  const u16* vsrc = Vb + (size_t)vc * NTOK + kv00 +
                    (((lane & 3) ^ ((lane >> 3) & 3)) * 8);

  // K-frag LDS byte offsets: row l31, slot (2kk+h)^(l31&15)
  int koff[8];
#pragma unroll
  for (int kk = 0; kk < 8; kk++)
    koff[kk] = l31 * 256 + (((2 * kk + h) ^ (l31 & 15)) << 4);
  // V-frag LDS byte offsets (add ct*2048): row ct*32+l31, slot (2b2+h)^((l31>>1)&3)
  int vo2[2];
#pragma unroll
  for (int b2 = 0; b2 < 2; b2++)
    vo2[b2] = l31 * 64 + (((2 * b2 + h) ^ ((l31 >> 1) & 3)) << 4);

#define STAGE(p)                                              \
  do {                                                        \
    u16* kb_ = (u16*)(smem + (p) * 16384) + w * 512;          \
    gl_lds16(ksrc, kb_);                                      \
    u16* vb_ = (u16*)(smem + (p) * 16384 + 8192) + w * 512;   \
    gl_lds16(vsrc, vb_);                                      \
    ksrc += 32 * CAv;                                         \
    vsrc += 32;                                               \
  } while (0)

  // prologue: stage tiles 0,1; confirm tile 0
  STAGE(0);
  STAGE(1);
  asm volatile("s_waitcnt vmcnt(2)" ::: "memory");
  __builtin_amdgcn_s_barrier();

  f32x16 o[4];
#pragma unroll
  for (int i = 0; i < 4; i++) o[i] = zero16();
  float m = -1e30f, lsum = 0.f;

  int pc = 0;
  for (int t = 0; t < 50; t++) {
    int ps = pc + 2; if (ps >= 3) ps -= 3;
    if (t < 48) STAGE(ps);
    const unsigned char* kbuf = smem + pc * 16384;
    const unsigned char* vbuf = smem + pc * 16384 + 8192;
    // QK^T (S^T): A = K rows from LDS, B = Q regs; 2 partial accs to halve
    // the dependent-MFMA latency chain
    __builtin_amdgcn_s_setprio(1);
    f32x16 sA = zero16(), sB = zero16();
#pragma unroll
    for (int kk = 0; kk < 8; kk += 2) {
      sh8 kfa = *(const sh8*)(kbuf + koff[kk]);
      sh8 kfb = *(const sh8*)(kbuf + koff[kk + 1]);
      sA = __builtin_amdgcn_mfma_f32_32x32x16_bf16(kfa, qf[kk], sA, 0, 0, 0);
      sB = __builtin_amdgcn_mfma_f32_32x32x16_bf16(kfb, qf[kk + 1], sB, 0, 0, 0);
    }
    __builtin_amdgcn_s_setprio(0);
    f32x16 s0;
#pragma unroll
    for (int r = 0; r < 16; r++) s0[r] = sA[r] + sB[r];
    // online softmax, exp2 domain (q lane-local; one xor32 hop)
    float pmax = -1e30f;
#pragma unroll
    for (int r = 0; r < 16; r++) pmax = fmaxf(pmax, s0[r]);
    pmax = fmaxf(pmax, __shfl_xor(pmax, 32));
    if (__any(pmax > m + 8.f)) {  // defer-max: P bounded by 2^8
      float mnew = fmaxf(m, pmax);
      float al = __builtin_exp2f(m - mnew);
#pragma unroll
      for (int i = 0; i < 16; i++) {
        o[0][i] *= al; o[1][i] *= al; o[2][i] *= al; o[3][i] *= al;
      }
      lsum *= al;
      m = mnew;
    }
    f32x16 p;
#pragma unroll
    for (int r = 0; r < 16; r++) p[r] = __builtin_exp2f(s0[r] - m);
    float ps_ = 0.f;
#pragma unroll
    for (int r = 0; r < 16; r++) ps_ += p[r];
    ps_ += __shfl_xor(ps_, 32);
    lsum += ps_;
    // pack P: pkm[rq][wd] holds kv rows 8*rq + 4h + {0..3}
    unsigned pkm[4][2];
#pragma unroll
    for (int rq = 0; rq < 4; rq++) {
      pkm[rq][0] = pk2(p[4 * rq + 0], p[4 * rq + 1]);
      pkm[rq][1] = pk2(p[4 * rq + 2], p[4 * rq + 3]);
    }
    // PV: per 16-kv step build B-frag (half local, half via xor-32)
#pragma unroll
    for (int b2 = 0; b2 < 2; b2++) {
      unsigned ow0 = h ? pkm[2 * b2 + 1][0] : pkm[2 * b2][0];
      unsigned ow1 = h ? pkm[2 * b2 + 1][1] : pkm[2 * b2][1];
      unsigned sd0 = h ? pkm[2 * b2][0] : pkm[2 * b2 + 1][0];
      unsigned sd1 = h ? pkm[2 * b2][1] : pkm[2 * b2 + 1][1];
      unsigned rv0 = (unsigned)__shfl_xor((int)sd0, 32);
      unsigned rv1 = (unsigned)__shfl_xor((int)sd1, 32);
      uint4v fw = {h ? rv0 : ow0, h ? rv1 : ow1, h ? ow0 : rv0, h ? ow1 : rv1};
      sh8 pf = __builtin_bit_cast(sh8, fw);
      __builtin_amdgcn_s_setprio(1);
#pragma unroll
      for (int ct = 0; ct < 4; ct++) {
        sh8 vf = *(const sh8*)(vbuf + ct * 2048 + vo2[b2]);
        o[ct] = __builtin_amdgcn_mfma_f32_32x32x16_bf16(vf, pf, o[ct], 0, 0, 0);
      }
      __builtin_amdgcn_s_setprio(0);
    }
    // confirm tile t+1 for next iter (keep t+2 DMA in flight)
    if (t < 48) {
      asm volatile("s_waitcnt vmcnt(2)" ::: "memory");
    } else {
      asm volatile("s_waitcnt vmcnt(0)" ::: "memory");
    }
    __builtin_amdgcn_s_barrier();
    pc = pc + 1; if (pc >= 3) pc = 0;
  }
#undef STAGE

  // epilogue: store unnormalized partial O (bf16) + m/l
  u16* op = Opart + (((size_t)kvq * BB + b) * NTOK + qb0 + w * 32 + l31) * CAv;
#pragma unroll
  for (int ct = 0; ct < 4; ct++)
#pragma unroll
    for (int rq = 0; rq < 4; rq++) {
      uint2v d = {pk2(o[ct][4 * rq + 0], o[ct][4 * rq + 1]),
                  pk2(o[ct][4 * rq + 2], o[ct][4 * rq + 3])};
      *(uint2v*)(op + ct * 32 + rq * 8 + h * 4) = d;
    }
  if (h == 0) {
    size_t mi = ((size_t)kvq * BB + b) * NTOK + qb0 + w * 32 + l31;
    Mpart[mi] = m;
    Lpart[mi] = lsum;
  }
}

// ---------------- output projection + 4-way kv merge + residual ----------------
__global__ __launch_bounds__(512) void outproj(const float* __restrict__ met,
                                               const float* __restrict__ woT,
                                               const float* __restrict__ bo,
                                               const u16* __restrict__ Opart,
                                               const float* __restrict__ Mpart,
                                               const float* __restrict__ Lpart,
                                               float* __restrict__ out) {
  const int bs = (blockIdx.x & 7) * 50 + (blockIdx.x >> 3);
  const int b = bs / 100;
  const int tokb = (bs % 100) * 64;
  const int tok = threadIdx.x & 63;
  const int chg = __builtin_amdgcn_readfirstlane(threadIdx.x >> 6);  // 0..7
  const size_t n = (size_t)b * NTOK + tokb + tok;
  const size_t PSTR = (size_t)BB * NTOK;
  // merge weights for the four kv-quarters
  float mq[4], lq[4];
#pragma unroll
  for (int i = 0; i < 4; i++) {
    mq[i] = Mpart[i * PSTR + n];
    lq[i] = Lpart[i * PSTR + n];
  }
  float M = fmaxf(fmaxf(mq[0], mq[1]), fmaxf(mq[2], mq[3]));
  float a0 = __builtin_exp2f(mq[0] - M), a1 = __builtin_exp2f(mq[1] - M);
  float a2 = __builtin_exp2f(mq[2] - M), a3 = __builtin_exp2f(mq[3] - M);
  float L = lq[0] * a0 + lq[1] * a1 + lq[2] * a2 + lq[3] * a3;
  float rL = 1.f / L;
  float w0 = a0 * rL, w1 = a1 * rL, w2 = a2 * rL, w3 = a3 * rL;
  const u16* o0 = Opart + n * CAv;
  const u16* o1 = Opart + (PSTR + n) * CAv;
  const u16* o2 = Opart + (2 * PSTR + n) * CAv;
  const u16* o3 = Opart + (3 * PSTR + n) * CAv;
  float acc[32];
#pragma unroll
  for (int j = 0; j < 32; j++) acc[j] = 0.f;
#pragma unroll 2
  for (int c8 = 0; c8 < 16; c8++) {
    sh8 va = *(const sh8*)(o0 + c8 * 8);
    sh8 vb = *(const sh8*)(o1 + c8 * 8);
    sh8 vc = *(const sh8*)(o2 + c8 * 8);
    sh8 vd = *(const sh8*)(o3 + c8 * 8);
#pragma unroll
    for (int e = 0; e < 8; e++) {
      float ov = bf2f((u16)va[e]) * w0 + bf2f((u16)vb[e]) * w1 +
                 bf2f((u16)vc[e]) * w2 + bf2f((u16)vd[e]) * w3;
      const float* wt = woT + (c8 * 8 + e) * CMv + chg * 32;
#pragma unroll
      for (int j = 0; j < 32; j++) acc[j] = fmaf(wt[j], ov, acc[j]);
    }
  }
#pragma unroll
  for (int j = 0; j < 32; j++) {
    int ch = chg * 32 + j;
    size_t idx = ((size_t)b * CMv + ch) * NTOK + tokb + tok;
    out[idx] = met[idx] + acc[j] + bo[ch];
  }
}

extern "C" void kernel_launch(void* const* d_in, const int* in_sizes, int n_in,
                              void* d_out, int out_size, void* d_ws, size_t ws_size,
                              hipStream_t stream) {
  const float* met = (const float*)d_in[0];
  const float* ter = (const float*)d_in[1];
  const float* wq = (const float*)d_in[2];
  const float* bq = (const float*)d_in[3];
  const float* wk = (const float*)d_in[4];
  const float* bk = (const float*)d_in[5];
  const float* wv = (const float*)d_in[6];
  const float* bv = (const float*)d_in[7];
  const float* wo = (const float*)d_in[8];
  const float* bo = (const float*)d_in[9];
  float* out = (float*)d_out;

  u16* Qtm = (u16*)d_ws;                                  // B*N*CA bf16
  u16* Ktm = Qtm + (size_t)BB * NTOK * CAv;               // B*N*CA bf16
  u16* Vcm = Ktm + (size_t)BB * NTOK * CAv;               // B*CA*N bf16
  u16* Opart = Vcm + (size_t)BB * NTOK * CAv;             // 4*B*N*CA bf16
  float* Mpart = (float*)(Opart + (size_t)4 * BB * NTOK * CAv);  // 4*B*N
  float* Lpart = Mpart + (size_t)4 * BB * NTOK;
  float* wqT = Lpart + (size_t)4 * BB * NTOK;
  float* wkT = wqT + 256 * 128;
  float* wvT = wkT + 64 * 128;
  float* woT = wvT + 64 * 128;

  prepw<<<dim3(32), dim3(256), 0, stream>>>(wq, wk, wv, wo, wqT, wkT, wvT, woT);
  qproj<<<dim3(400), dim3(256), 0, stream>>>(met, wqT, bq, Qtm);
  kvproj<<<dim3(400), dim3(512), 0, stream>>>(ter, wkT, bk, wvT, bv, Ktm, Vcm);
  attn<<<dim3(400), dim3(512), 0, stream>>>(Qtm, Ktm, Vcm, Opart, Mpart, Lpart);
  outproj<<<dim3(400), dim3(512), 0, stream>>>(met, woT, bo, Opart, Mpart, Lpart, out);
}

// Round 8
// 282.170 us; speedup vs baseline: 1.3067x; 1.3067x over previous
//
#include <hip/hip_runtime.h>
#include <hip/hip_bf16.h>

#define BB 4
#define CMv 256
#define CTv 64
#define CAv 128
#define NTOK 6400
/* 128^-0.5 * log2(e): softmax runs in exp2 domain */
#define QSCL 0.12753102198064644f

typedef unsigned short u16;
typedef __attribute__((ext_vector_type(8))) short sh8;     // 8 bf16
typedef __attribute__((ext_vector_type(4))) float f32x4;
typedef __attribute__((ext_vector_type(16))) float f32x16;
typedef __attribute__((ext_vector_type(4))) unsigned uint4v;
typedef __attribute__((ext_vector_type(2))) unsigned uint2v;

__device__ __forceinline__ u16 f2bf(float f) {
  return __builtin_bit_cast(u16, __float2bfloat16(f));
}
__device__ __forceinline__ float bf2f(u16 x) {
  unsigned u = ((unsigned)x) << 16;
  return __builtin_bit_cast(float, u);
}
__device__ __forceinline__ unsigned pk2(float a, float b) {
  return ((unsigned)f2bf(b) << 16) | (unsigned)f2bf(a);
}
__device__ __forceinline__ f32x16 zero16() {
  f32x16 z;
#pragma unroll
  for (int i = 0; i < 16; i++) z[i] = 0.f;
  return z;
}
typedef const __attribute__((address_space(1))) unsigned int* gas_p;
typedef __attribute__((address_space(3))) unsigned int* las_p;
__device__ __forceinline__ void gl_lds16(const u16* g, u16* l) {
  __builtin_amdgcn_global_load_lds((gas_p)g, (las_p)l, 16, 0, 0);
}

// ---------------- weight transpose prep ----------------
__global__ __launch_bounds__(256) void prepw(const float* __restrict__ wq,
                                             const float* __restrict__ wk,
                                             const float* __restrict__ wv,
                                             const float* __restrict__ wo,
                                             float* __restrict__ wqT,
                                             float* __restrict__ wkT,
                                             float* __restrict__ wvT,
                                             float* __restrict__ woT) {
  int i0 = blockIdx.x * 256 + threadIdx.x;
  for (int idx = i0; idx < 256 * 128; idx += 32 * 256) {
    int ch = idx & 127, cin = idx >> 7;
    wqT[idx] = wq[ch * CMv + cin];
  }
  for (int idx = i0; idx < 64 * 128; idx += 32 * 256) {
    int ch = idx & 127, cin = idx >> 7;
    wkT[idx] = wk[ch * CTv + cin];
    wvT[idx] = wv[ch * CTv + cin];
  }
  for (int idx = i0; idx < 128 * 256; idx += 32 * 256) {
    int ch = idx & 255, c = idx >> 8;
    woT[idx] = wo[ch * CAv + c];
  }
}

// ---------------- Q projection (scale+log2e folded) ----------------
__global__ __launch_bounds__(256) void qproj(const float* __restrict__ met,
                                             const float* __restrict__ wqT,
                                             const float* __restrict__ bq,
                                             u16* __restrict__ Qtm) {
  const int b = blockIdx.x / 100;
  const int tokb = (blockIdx.x % 100) * 64;
  const int tok = threadIdx.x & 63;
  const int chg = __builtin_amdgcn_readfirstlane(threadIdx.x >> 6);  // 0..3
  const float* wt = wqT + chg * 32;
  const float* mp = met + (size_t)b * CMv * NTOK + tokb + tok;
  float acc[32];
#pragma unroll
  for (int j = 0; j < 32; j++) acc[j] = bq[chg * 32 + j];
#pragma unroll 8
  for (int cin = 0; cin < CMv; cin++) {
    float x = mp[(size_t)cin * NTOK];
#pragma unroll
    for (int j = 0; j < 32; j++) acc[j] = fmaf(wt[cin * CAv + j], x, acc[j]);
  }
  u16* qp = Qtm + ((size_t)b * NTOK + tokb + tok) * CAv + chg * 32;
#pragma unroll
  for (int v = 0; v < 4; v++) {
    sh8 pkv;
#pragma unroll
    for (int e = 0; e < 8; e++) pkv[e] = (short)f2bf(acc[v * 8 + e] * QSCL);
    *(sh8*)(qp + v * 8) = pkv;
  }
}

// ---------------- K,V projections ----------------
__global__ __launch_bounds__(512) void kvproj(const float* __restrict__ ter,
                                              const float* __restrict__ wkT,
                                              const float* __restrict__ bk,
                                              const float* __restrict__ wvT,
                                              const float* __restrict__ bv,
                                              u16* __restrict__ Ktm,
                                              u16* __restrict__ Vcm) {
  const int b = blockIdx.x / 100;
  const int tokb = (blockIdx.x % 100) * 64;
  const int tok = threadIdx.x & 63;
  const int grp = __builtin_amdgcn_readfirstlane(threadIdx.x >> 6);  // 0..7
  const bool isV = grp >= 4;
  const int chg = isV ? (grp - 4) : grp;
  const float* wt = (isV ? wvT : wkT) + chg * 32;
  const float* bias = isV ? bv : bk;
  const float* tp = ter + (size_t)b * CTv * NTOK + tokb + tok;
  float acc[32];
#pragma unroll
  for (int j = 0; j < 32; j++) acc[j] = bias[chg * 32 + j];
#pragma unroll 8
  for (int cin = 0; cin < CTv; cin++) {
    float x = tp[(size_t)cin * NTOK];
#pragma unroll
    for (int j = 0; j < 32; j++) acc[j] = fmaf(wt[cin * CAv + j], x, acc[j]);
  }
  if (!isV) {
    u16* kp = Ktm + ((size_t)b * NTOK + tokb + tok) * CAv + chg * 32;
#pragma unroll
    for (int v = 0; v < 4; v++) {
      sh8 pkv;
#pragma unroll
      for (int e = 0; e < 8; e++) pkv[e] = (short)f2bf(acc[v * 8 + e]);
      *(sh8*)(kp + v * 8) = pkv;
    }
  } else {
    u16* vp = Vcm + ((size_t)b * CAv + chg * 32) * NTOK + tokb + tok;
#pragma unroll
    for (int j = 0; j < 32; j++) vp[(size_t)j * NTOK] = f2bf(acc[j]);
  }
}

// ---------------- flash attention ----------------
// Grid 400 = 25 q-tiles x 16 groups (g = b*4 + kvq); blockIdx = qt*16 + g so a
// (b,kvq) group's K/V quarter pins to XCD g%8. Block: 8 waves x 32 q-rows
// (Q_T=256) -- each staged K/V byte serves 256 q-rows. Waves share each 32-kv
// K/V tile in LDS (triple-buffered, staged 2 ahead via global_load_lds;
// counted vmcnt(2) + one raw s_barrier per tile -- queue never drains).
// launch_bounds(512,2): VGPR cap 256 -- (512,4) capped at 64 and spilled the
// f32x16 accumulators to scratch (R7: WRITE_SIZE 2x, FETCH 2x, 60% slower).
// Partial O (unnormalized bf16) + m/l per kv-quarter; merged in outproj.
__global__ __launch_bounds__(512, 2) void attn(const u16* __restrict__ Qtm,
                                               const u16* __restrict__ Ktm,
                                               const u16* __restrict__ Vcm,
                                               u16* __restrict__ Opart,
                                               float* __restrict__ Mpart,
                                               float* __restrict__ Lpart) {
  __shared__ __align__(16) unsigned char smem[49152];  // 3 x (K 8KB | V 8KB)

  const int tid = threadIdx.x;
  const int w = tid >> 6;        // q-subtile 0..7
  const int lane = tid & 63;
  const int l31 = lane & 31;
  const int h = lane >> 5;

  const int g = blockIdx.x & 15;
  const int qt = blockIdx.x >> 4;      // 0..24
  const int b = g >> 2;
  const int kvq = g & 3;
  const int qb0 = qt * 256;
  const int kv00 = kvq * 1600;

  const u16* Qb = Qtm + ((size_t)b * NTOK + qb0 + w * 32 + l31) * CAv;
  const u16* Kb = Ktm + (size_t)b * NTOK * CAv;
  const u16* Vb = Vcm + (size_t)b * CAv * NTOK;

  // Q fragments (B-operand): col=q=l31, k = kk*16 + 8h + j
  sh8 qf[8];
#pragma unroll
  for (int kk = 0; kk < 8; kk++) qf[kk] = *(const sh8*)(Qb + kk * 16 + h * 8);

  // K DMA source (1 inst/wave, 4 rows x 256B): row kr = w*4 + (lane>>4),
  // LDS slot = lane&15, source chunk = (lane&15) ^ (kr&15)
  const int kr = w * 4 + (lane >> 4);
  const u16* ksrc = Kb + ((size_t)kv00 + kr) * CAv + (((lane & 15) ^ (kr & 15)) * 8);
  // V DMA source (1 inst/wave, 16 rows x 64B): c = w*16 + (lane>>2),
  // slot = lane&3, chunk = (lane&3) ^ ((c>>1)&3) = (lane&3) ^ ((lane>>3)&3)
  const int vc = w * 16 + (lane >> 2);
  const u16* vsrc = Vb + (size_t)vc * NTOK + kv00 +
                    (((lane & 3) ^ ((lane >> 3) & 3)) * 8);

  // K-frag LDS byte offsets: row l31, slot (2kk+h)^(l31&15)
  int koff[8];
#pragma unroll
  for (int kk = 0; kk < 8; kk++)
    koff[kk] = l31 * 256 + (((2 * kk + h) ^ (l31 & 15)) << 4);
  // V-frag LDS byte offsets (add ct*2048): row ct*32+l31, slot (2b2+h)^((l31>>1)&3)
  int vo2[2];
#pragma unroll
  for (int b2 = 0; b2 < 2; b2++)
    vo2[b2] = l31 * 64 + (((2 * b2 + h) ^ ((l31 >> 1) & 3)) << 4);

#define STAGE(p)                                              \
  do {                                                        \
    u16* kb_ = (u16*)(smem + (p) * 16384) + w * 512;          \
    gl_lds16(ksrc, kb_);                                      \
    u16* vb_ = (u16*)(smem + (p) * 16384 + 8192) + w * 512;   \
    gl_lds16(vsrc, vb_);                                      \
    ksrc += 32 * CAv;                                         \
    vsrc += 32;                                               \
  } while (0)

  // prologue: stage tiles 0,1; confirm tile 0
  STAGE(0);
  STAGE(1);
  asm volatile("s_waitcnt vmcnt(2)" ::: "memory");
  __builtin_amdgcn_s_barrier();

  f32x16 o[4];
#pragma unroll
  for (int i = 0; i < 4; i++) o[i] = zero16();
  float m = -1e30f, lsum = 0.f;

  int pc = 0;
  for (int t = 0; t < 50; t++) {
    int ps = pc + 2; if (ps >= 3) ps -= 3;
    if (t < 48) STAGE(ps);
    const unsigned char* kbuf = smem + pc * 16384;
    const unsigned char* vbuf = smem + pc * 16384 + 8192;
    // QK^T (S^T): A = K rows from LDS, B = Q regs; 2 partial accs to halve
    // the dependent-MFMA latency chain
    __builtin_amdgcn_s_setprio(1);
    f32x16 sA = zero16(), sB = zero16();
#pragma unroll
    for (int kk = 0; kk < 8; kk += 2) {
      sh8 kfa = *(const sh8*)(kbuf + koff[kk]);
      sh8 kfb = *(const sh8*)(kbuf + koff[kk + 1]);
      sA = __builtin_amdgcn_mfma_f32_32x32x16_bf16(kfa, qf[kk], sA, 0, 0, 0);
      sB = __builtin_amdgcn_mfma_f32_32x32x16_bf16(kfb, qf[kk + 1], sB, 0, 0, 0);
    }
    __builtin_amdgcn_s_setprio(0);
    f32x16 s0;
#pragma unroll
    for (int r = 0; r < 16; r++) s0[r] = sA[r] + sB[r];
    // online softmax, exp2 domain (q lane-local; one xor32 hop)
    float pmax = -1e30f;
#pragma unroll
    for (int r = 0; r < 16; r++) pmax = fmaxf(pmax, s0[r]);
    pmax = fmaxf(pmax, __shfl_xor(pmax, 32));
    if (__any(pmax > m + 8.f)) {  // defer-max: P bounded by 2^8
      float mnew = fmaxf(m, pmax);
      float al = __builtin_exp2f(m - mnew);
#pragma unroll
      for (int i = 0; i < 16; i++) {
        o[0][i] *= al; o[1][i] *= al; o[2][i] *= al; o[3][i] *= al;
      }
      lsum *= al;
      m = mnew;
    }
    f32x16 p;
#pragma unroll
    for (int r = 0; r < 16; r++) p[r] = __builtin_exp2f(s0[r] - m);
    float ps_ = 0.f;
#pragma unroll
    for (int r = 0; r < 16; r++) ps_ += p[r];
    ps_ += __shfl_xor(ps_, 32);
    lsum += ps_;
    // pack P: pkm[rq][wd] holds kv rows 8*rq + 4h + {0..3}
    unsigned pkm[4][2];
#pragma unroll
    for (int rq = 0; rq < 4; rq++) {
      pkm[rq][0] = pk2(p[4 * rq + 0], p[4 * rq + 1]);
      pkm[rq][1] = pk2(p[4 * rq + 2], p[4 * rq + 3]);
    }
    // PV: per 16-kv step build B-frag (half local, half via xor-32)
#pragma unroll
    for (int b2 = 0; b2 < 2; b2++) {
      unsigned ow0 = h ? pkm[2 * b2 + 1][0] : pkm[2 * b2][0];
      unsigned ow1 = h ? pkm[2 * b2 + 1][1] : pkm[2 * b2][1];
      unsigned sd0 = h ? pkm[2 * b2][0] : pkm[2 * b2 + 1][0];
      unsigned sd1 = h ? pkm[2 * b2][1] : pkm[2 * b2 + 1][1];
      unsigned rv0 = (unsigned)__shfl_xor((int)sd0, 32);
      unsigned rv1 = (unsigned)__shfl_xor((int)sd1, 32);
      uint4v fw = {h ? rv0 : ow0, h ? rv1 : ow1, h ? ow0 : rv0, h ? ow1 : rv1};
      sh8 pf = __builtin_bit_cast(sh8, fw);
      __builtin_amdgcn_s_setprio(1);
#pragma unroll
      for (int ct = 0; ct < 4; ct++) {
        sh8 vf = *(const sh8*)(vbuf + ct * 2048 + vo2[b2]);
        o[ct] = __builtin_amdgcn_mfma_f32_32x32x16_bf16(vf, pf, o[ct], 0, 0, 0);
      }
      __builtin_amdgcn_s_setprio(0);
    }
    // confirm tile t+1 for next iter (keep t+2 DMA in flight)
    if (t < 48) {
      asm volatile("s_waitcnt vmcnt(2)" ::: "memory");
    } else {
      asm volatile("s_waitcnt vmcnt(0)" ::: "memory");
    }
    __builtin_amdgcn_s_barrier();
    pc = pc + 1; if (pc >= 3) pc = 0;
  }
#undef STAGE

  // epilogue: store unnormalized partial O (bf16) + m/l
  u16* op = Opart + (((size_t)kvq * BB + b) * NTOK + qb0 + w * 32 + l31) * CAv;
#pragma unroll
  for (int ct = 0; ct < 4; ct++)
#pragma unroll
    for (int rq = 0; rq < 4; rq++) {
      uint2v d = {pk2(o[ct][4 * rq + 0], o[ct][4 * rq + 1]),
                  pk2(o[ct][4 * rq + 2], o[ct][4 * rq + 3])};
      *(uint2v*)(op + ct * 32 + rq * 8 + h * 4) = d;
    }
  if (h == 0) {
    size_t mi = ((size_t)kvq * BB + b) * NTOK + qb0 + w * 32 + l31;
    Mpart[mi] = m;
    Lpart[mi] = lsum;
  }
}

// ---------------- output projection + 4-way kv merge + residual ----------------
__global__ __launch_bounds__(512) void outproj(const float* __restrict__ met,
                                               const float* __restrict__ woT,
                                               const float* __restrict__ bo,
                                               const u16* __restrict__ Opart,
                                               const float* __restrict__ Mpart,
                                               const float* __restrict__ Lpart,
                                               float* __restrict__ out) {
  const int bs = (blockIdx.x & 7) * 50 + (blockIdx.x >> 3);
  const int b = bs / 100;
  const int tokb = (bs % 100) * 64;
  const int tok = threadIdx.x & 63;
  const int chg = __builtin_amdgcn_readfirstlane(threadIdx.x >> 6);  // 0..7
  const size_t n = (size_t)b * NTOK + tokb + tok;
  const size_t PSTR = (size_t)BB * NTOK;
  // merge weights for the four kv-quarters
  float mq[4], lq[4];
#pragma unroll
  for (int i = 0; i < 4; i++) {
    mq[i] = Mpart[i * PSTR + n];
    lq[i] = Lpart[i * PSTR + n];
  }
  float M = fmaxf(fmaxf(mq[0], mq[1]), fmaxf(mq[2], mq[3]));
  float a0 = __builtin_exp2f(mq[0] - M), a1 = __builtin_exp2f(mq[1] - M);
  float a2 = __builtin_exp2f(mq[2] - M), a3 = __builtin_exp2f(mq[3] - M);
  float L = lq[0] * a0 + lq[1] * a1 + lq[2] * a2 + lq[3] * a3;
  float rL = 1.f / L;
  float w0 = a0 * rL, w1 = a1 * rL, w2 = a2 * rL, w3 = a3 * rL;
  const u16* o0 = Opart + n * CAv;
  const u16* o1 = Opart + (PSTR + n) * CAv;
  const u16* o2 = Opart + (2 * PSTR + n) * CAv;
  const u16* o3 = Opart + (3 * PSTR + n) * CAv;
  float acc[32];
#pragma unroll
  for (int j = 0; j < 32; j++) acc[j] = 0.f;
#pragma unroll 2
  for (int c8 = 0; c8 < 16; c8++) {
    sh8 va = *(const sh8*)(o0 + c8 * 8);
    sh8 vb = *(const sh8*)(o1 + c8 * 8);
    sh8 vc = *(const sh8*)(o2 + c8 * 8);
    sh8 vd = *(const sh8*)(o3 + c8 * 8);
#pragma unroll
    for (int e = 0; e < 8; e++) {
      float ov = bf2f((u16)va[e]) * w0 + bf2f((u16)vb[e]) * w1 +
                 bf2f((u16)vc[e]) * w2 + bf2f((u16)vd[e]) * w3;
      const float* wt = woT + (c8 * 8 + e) * CMv + chg * 32;
#pragma unroll
      for (int j = 0; j < 32; j++) acc[j] = fmaf(wt[j], ov, acc[j]);
    }
  }
#pragma unroll
  for (int j = 0; j < 32; j++) {
    int ch = chg * 32 + j;
    size_t idx = ((size_t)b * CMv + ch) * NTOK + tokb + tok;
    out[idx] = met[idx] + acc[j] + bo[ch];
  }
}

extern "C" void kernel_launch(void* const* d_in, const int* in_sizes, int n_in,
                              void* d_out, int out_size, void* d_ws, size_t ws_size,
                              hipStream_t stream) {
  const float* met = (const float*)d_in[0];
  const float* ter = (const float*)d_in[1];
  const float* wq = (const float*)d_in[2];
  const float* bq = (const float*)d_in[3];
  const float* wk = (const float*)d_in[4];
  const float* bk = (const float*)d_in[5];
  const float* wv = (const float*)d_in[6];
  const float* bv = (const float*)d_in[7];
  const float* wo = (const float*)d_in[8];
  const float* bo = (const float*)d_in[9];
  float* out = (float*)d_out;

  u16* Qtm = (u16*)d_ws;                                  // B*N*CA bf16
  u16* Ktm = Qtm + (size_t)BB * NTOK * CAv;               // B*N*CA bf16
  u16* Vcm = Ktm + (size_t)BB * NTOK * CAv;               // B*CA*N bf16
  u16* Opart = Vcm + (size_t)BB * NTOK * CAv;             // 4*B*N*CA bf16
  float* Mpart = (float*)(Opart + (size_t)4 * BB * NTOK * CAv);  // 4*B*N
  float* Lpart = Mpart + (size_t)4 * BB * NTOK;
  float* wqT = Lpart + (size_t)4 * BB * NTOK;
  float* wkT = wqT + 256 * 128;
  float* wvT = wkT + 64 * 128;
  float* woT = wvT + 64 * 128;

  prepw<<<dim3(32), dim3(256), 0, stream>>>(wq, wk, wv, wo, wqT, wkT, wvT, woT);
  qproj<<<dim3(400), dim3(256), 0, stream>>>(met, wqT, bq, Qtm);
  kvproj<<<dim3(400), dim3(512), 0, stream>>>(ter, wkT, bk, wvT, bv, Ktm, Vcm);
  attn<<<dim3(400), dim3(512), 0, stream>>>(Qtm, Ktm, Vcm, Opart, Mpart, Lpart);
  outproj<<<dim3(400), dim3(512), 0, stream>>>(met, woT, bo, Opart, Mpart, Lpart, out);
}

// Round 10
// 268.381 us; speedup vs baseline: 1.3738x; 1.0514x over previous
//
#include <hip/hip_runtime.h>
#include <hip/hip_bf16.h>

#define BB 4
#define CMv 256
#define CTv 64
#define CAv 128
#define NTOK 6400
#define KVSPLIT 5
#define KVRANGE 1280   /* NTOK/KVSPLIT */
#define NTILES 20      /* KVRANGE/64 */
/* 128^-0.5 * log2(e): softmax runs in exp2 domain */
#define QSCL 0.12753102198064644f

typedef unsigned short u16;
typedef __attribute__((ext_vector_type(8))) short sh8;     // 8 bf16
typedef __attribute__((ext_vector_type(4))) float f32x4;
typedef __attribute__((ext_vector_type(16))) float f32x16;
typedef __attribute__((ext_vector_type(4))) unsigned uint4v;
typedef __attribute__((ext_vector_type(2))) unsigned uint2v;

__device__ __forceinline__ u16 f2bf(float f) {
  return __builtin_bit_cast(u16, __float2bfloat16(f));
}
__device__ __forceinline__ float bf2f(u16 x) {
  unsigned u = ((unsigned)x) << 16;
  return __builtin_bit_cast(float, u);
}
__device__ __forceinline__ unsigned pk2(float a, float b) {
  return ((unsigned)f2bf(b) << 16) | (unsigned)f2bf(a);
}
__device__ __forceinline__ f32x16 zero16() {
  f32x16 z;
#pragma unroll
  for (int i = 0; i < 16; i++) z[i] = 0.f;
  return z;
}
typedef const __attribute__((address_space(1))) unsigned int* gas_p;
typedef __attribute__((address_space(3))) unsigned int* las_p;
__device__ __forceinline__ void gl_lds16(const u16* g, u16* l) {
  __builtin_amdgcn_global_load_lds((gas_p)g, (las_p)l, 16, 0, 0);
}

// ---------------- weight transpose prep ----------------
__global__ __launch_bounds__(256) void prepw(const float* __restrict__ wq,
                                             const float* __restrict__ wk,
                                             const float* __restrict__ wv,
                                             const float* __restrict__ wo,
                                             float* __restrict__ wqT,
                                             float* __restrict__ wkT,
                                             float* __restrict__ wvT,
                                             float* __restrict__ woT) {
  int i0 = blockIdx.x * 256 + threadIdx.x;
  for (int idx = i0; idx < 256 * 128; idx += 32 * 256) {
    int ch = idx & 127, cin = idx >> 7;
    wqT[idx] = wq[ch * CMv + cin];
  }
  for (int idx = i0; idx < 64 * 128; idx += 32 * 256) {
    int ch = idx & 127, cin = idx >> 7;
    wkT[idx] = wk[ch * CTv + cin];
    wvT[idx] = wv[ch * CTv + cin];
  }
  for (int idx = i0; idx < 128 * 256; idx += 32 * 256) {
    int ch = idx & 255, c = idx >> 8;
    woT[idx] = wo[ch * CAv + c];
  }
}

// ---------------- Q projection (scale+log2e folded) ----------------
__global__ __launch_bounds__(256) void qproj(const float* __restrict__ met,
                                             const float* __restrict__ wqT,
                                             const float* __restrict__ bq,
                                             u16* __restrict__ Qtm) {
  const int b = blockIdx.x / 100;
  const int tokb = (blockIdx.x % 100) * 64;
  const int tok = threadIdx.x & 63;
  const int chg = __builtin_amdgcn_readfirstlane(threadIdx.x >> 6);  // 0..3
  const float* wt = wqT + chg * 32;
  const float* mp = met + (size_t)b * CMv * NTOK + tokb + tok;
  float acc[32];
#pragma unroll
  for (int j = 0; j < 32; j++) acc[j] = bq[chg * 32 + j];
#pragma unroll 8
  for (int cin = 0; cin < CMv; cin++) {
    float x = mp[(size_t)cin * NTOK];
#pragma unroll
    for (int j = 0; j < 32; j++) acc[j] = fmaf(wt[cin * CAv + j], x, acc[j]);
  }
  u16* qp = Qtm + ((size_t)b * NTOK + tokb + tok) * CAv + chg * 32;
#pragma unroll
  for (int v = 0; v < 4; v++) {
    sh8 pkv;
#pragma unroll
    for (int e = 0; e < 8; e++) pkv[e] = (short)f2bf(acc[v * 8 + e] * QSCL);
    *(sh8*)(qp + v * 8) = pkv;
  }
}

// ---------------- K,V projections ----------------
__global__ __launch_bounds__(512) void kvproj(const float* __restrict__ ter,
                                              const float* __restrict__ wkT,
                                              const float* __restrict__ bk,
                                              const float* __restrict__ wvT,
                                              const float* __restrict__ bv,
                                              u16* __restrict__ Ktm,
                                              u16* __restrict__ Vcm) {
  const int b = blockIdx.x / 100;
  const int tokb = (blockIdx.x % 100) * 64;
  const int tok = threadIdx.x & 63;
  const int grp = __builtin_amdgcn_readfirstlane(threadIdx.x >> 6);  // 0..7
  const bool isV = grp >= 4;
  const int chg = isV ? (grp - 4) : grp;
  const float* wt = (isV ? wvT : wkT) + chg * 32;
  const float* bias = isV ? bv : bk;
  const float* tp = ter + (size_t)b * CTv * NTOK + tokb + tok;
  float acc[32];
#pragma unroll
  for (int j = 0; j < 32; j++) acc[j] = bias[chg * 32 + j];
#pragma unroll 8
  for (int cin = 0; cin < CTv; cin++) {
    float x = tp[(size_t)cin * NTOK];
#pragma unroll
    for (int j = 0; j < 32; j++) acc[j] = fmaf(wt[cin * CAv + j], x, acc[j]);
  }
  if (!isV) {
    u16* kp = Ktm + ((size_t)b * NTOK + tokb + tok) * CAv + chg * 32;
#pragma unroll
    for (int v = 0; v < 4; v++) {
      sh8 pkv;
#pragma unroll
      for (int e = 0; e < 8; e++) pkv[e] = (short)f2bf(acc[v * 8 + e]);
      *(sh8*)(kp + v * 8) = pkv;
    }
  } else {
    u16* vp = Vcm + ((size_t)b * CAv + chg * 32) * NTOK + tokb + tok;
#pragma unroll
    for (int j = 0; j < 32; j++) vp[(size_t)j * NTOK] = f2bf(acc[j]);
  }
}

// ---------------- flash attention ----------------
// Grid 500 = 25 q-tiles x 20 groups (g = b*5 + kvq) -> ~2 blocks/CU uniformly.
// Block: 8 waves x 32 q-rows (Q_T=256). KVBLK=64: 20 tiles/block, double-
// buffered 2x32KB LDS staged via global_load_lds 1 tile ahead; one
// vmcnt(0)+s_barrier per 64-kv tile. QK: two independent S accumulators
// (kv 0-31 / 32-63). K rows 256B, XOR slot^(row&15); V rows 128B, XOR
// slot^(c&7). R9 BUG FIX: each K row-group gets its OWN source pointer with
// its OWN XOR key ((kr+4)&15 != kr&15; V's +8 stride preserved c&7, K's +4
// did not) -- rule: DMA-source permutation must equal read permutation PER
// INSTRUCTION. Partial O bf16 + m/l per kv-fifth; merge in outproj.
__global__ __launch_bounds__(512, 2) void attn(const u16* __restrict__ Qtm,
                                               const u16* __restrict__ Ktm,
                                               const u16* __restrict__ Vcm,
                                               u16* __restrict__ Opart,
                                               float* __restrict__ Mpart,
                                               float* __restrict__ Lpart) {
  __shared__ __align__(16) unsigned char smem[65536];  // 2 x (K 16KB | V 16KB)

  const int tid = threadIdx.x;
  const int w = tid >> 6;        // wave 0..7
  const int lane = tid & 63;
  const int l31 = lane & 31;
  const int h = lane >> 5;

  const int g = blockIdx.x % 20;
  const int qt = blockIdx.x / 20;      // 0..24
  const int b = g / KVSPLIT;
  const int kvq = g % KVSPLIT;
  const int qb0 = qt * 256;
  const int kv00 = kvq * KVRANGE;

  const u16* Qb = Qtm + ((size_t)b * NTOK + qb0 + w * 32 + l31) * CAv;
  const u16* Kb = Ktm + (size_t)b * NTOK * CAv;
  const u16* Vb = Vcm + (size_t)b * CAv * NTOK;

  // Q fragments (B-operand): col=q=l31, k = kk*16 + 8h + j
  sh8 qf[8];
#pragma unroll
  for (int kk = 0; kk < 8; kk++) qf[kk] = *(const sh8*)(Qb + kk * 16 + h * 8);

  // K DMA (2 inst/wave, 8 rows x 256B): row groups kr0 = w*8+(lane>>4) and
  // kr1 = kr0+4, EACH with its own XOR key (row&15). Advance 64 rows keeps keys.
  const int kr0 = w * 8 + (lane >> 4);
  const int kr1 = kr0 + 4;
  const u16* ksrc0 = Kb + ((size_t)kv00 + kr0) * CAv + (((lane & 15) ^ (kr0 & 15)) * 8);
  const u16* ksrc1 = Kb + ((size_t)kv00 + kr1) * CAv + (((lane & 15) ^ (kr1 & 15)) * 8);
  // V DMA (2 inst/wave, 16 rows x 128B): c = w*16 + (lane>>3) (+8);
  // slot = lane&7, chunk = (lane&7) ^ (c&7); (c+8)&7 == c&7 so one key works.
  const int vc = w * 16 + (lane >> 3);
  const u16* vsrc = Vb + (size_t)vc * NTOK + kv00 +
                    (((lane & 7) ^ ((lane >> 3) & 7)) * 8);

  // K-frag LDS byte offsets (s0 half: rows l31; s1: +32 rows = +8192B;
  // (32+l31)&15 == l31&15 so same XOR key)
  int koff[8];
#pragma unroll
  for (int kk = 0; kk < 8; kk++)
    koff[kk] = l31 * 256 + (((2 * kk + h) ^ (l31 & 15)) << 4);
  // V-frag LDS byte offsets per 16-kv step b2=0..3 (add ct*4096):
  // row c = ct*32 + l31 (c&7 == l31&7), slot (2*b2+h)^(l31&7)
  int voff[4];
#pragma unroll
  for (int b2 = 0; b2 < 4; b2++)
    voff[b2] = l31 * 128 + (((2 * b2 + h) ^ (l31 & 7)) << 4);

#define STAGE(p)                                               \
  do {                                                         \
    u16* kb_ = (u16*)(smem + (p) * 32768) + w * 1024;          \
    gl_lds16(ksrc0, kb_);                                      \
    gl_lds16(ksrc1, kb_ + 512);                                \
    u16* vb_ = (u16*)(smem + (p) * 32768 + 16384) + w * 1024;  \
    gl_lds16(vsrc, vb_);                                       \
    gl_lds16(vsrc + (size_t)8 * NTOK, vb_ + 512);              \
    ksrc0 += 64 * CAv;                                         \
    ksrc1 += 64 * CAv;                                         \
    vsrc += 64;                                                \
  } while (0)

  // prologue: stage tile 0, confirm
  STAGE(0);
  asm volatile("s_waitcnt vmcnt(0)" ::: "memory");
  __builtin_amdgcn_s_barrier();

  f32x16 o[4];
#pragma unroll
  for (int i = 0; i < 4; i++) o[i] = zero16();
  float m = -1e30f, lsum = 0.f;

  int buf = 0;
  for (int t = 0; t < NTILES; t++) {
    if (t < NTILES - 1) STAGE(buf ^ 1);   // issue next tile's DMA
    const unsigned char* kbuf = smem + buf * 32768;
    const unsigned char* vbuf = kbuf + 16384;
    // QK^T: two independent 32kv x 32q subtiles (kv 0-31 -> s0, 32-63 -> s1)
    __builtin_amdgcn_s_setprio(1);
    f32x16 s0 = zero16(), s1 = zero16();
#pragma unroll
    for (int kk = 0; kk < 8; kk++) {
      sh8 kfa = *(const sh8*)(kbuf + koff[kk]);
      sh8 kfb = *(const sh8*)(kbuf + 8192 + koff[kk]);
      s0 = __builtin_amdgcn_mfma_f32_32x32x16_bf16(kfa, qf[kk], s0, 0, 0, 0);
      s1 = __builtin_amdgcn_mfma_f32_32x32x16_bf16(kfb, qf[kk], s1, 0, 0, 0);
    }
    __builtin_amdgcn_s_setprio(0);
    // online softmax over 64 kv, exp2 domain (q lane-local; one xor32 hop)
    float pmax = -1e30f;
#pragma unroll
    for (int r = 0; r < 16; r++) pmax = fmaxf(pmax, fmaxf(s0[r], s1[r]));
    pmax = fmaxf(pmax, __shfl_xor(pmax, 32));
    if (__any(pmax > m + 8.f)) {  // defer-max: P bounded by 2^8
      float mnew = fmaxf(m, pmax);
      float al = __builtin_exp2f(m - mnew);
#pragma unroll
      for (int i = 0; i < 16; i++) {
        o[0][i] *= al; o[1][i] *= al; o[2][i] *= al; o[3][i] *= al;
      }
      lsum *= al;
      m = mnew;
    }
    f32x16 p0, p1;
#pragma unroll
    for (int r = 0; r < 16; r++) {
      p0[r] = __builtin_exp2f(s0[r] - m);
      p1[r] = __builtin_exp2f(s1[r] - m);
    }
    float ps_ = 0.f;
#pragma unroll
    for (int r = 0; r < 16; r++) ps_ += p0[r] + p1[r];
    ps_ += __shfl_xor(ps_, 32);
    lsum += ps_;
    // pack P halves: pkm[x][rq][wd] holds kv rows x*32 + 8*rq + 4h + {0..3}
    unsigned pkm0[4][2], pkm1[4][2];
#pragma unroll
    for (int rq = 0; rq < 4; rq++) {
      pkm0[rq][0] = pk2(p0[4 * rq + 0], p0[4 * rq + 1]);
      pkm0[rq][1] = pk2(p0[4 * rq + 2], p0[4 * rq + 3]);
      pkm1[rq][0] = pk2(p1[4 * rq + 0], p1[4 * rq + 1]);
      pkm1[rq][1] = pk2(p1[4 * rq + 2], p1[4 * rq + 3]);
    }
    // PV: 4 16-kv steps; steps 0-1 from pkm0, 2-3 from pkm1
#pragma unroll
    for (int x = 0; x < 2; x++) {
#pragma unroll
      for (int b2i = 0; b2i < 2; b2i++) {
        unsigned ow0, ow1, sd0, sd1;
        if (x == 0) {
          ow0 = h ? pkm0[2 * b2i + 1][0] : pkm0[2 * b2i][0];
          ow1 = h ? pkm0[2 * b2i + 1][1] : pkm0[2 * b2i][1];
          sd0 = h ? pkm0[2 * b2i][0] : pkm0[2 * b2i + 1][0];
          sd1 = h ? pkm0[2 * b2i][1] : pkm0[2 * b2i + 1][1];
        } else {
          ow0 = h ? pkm1[2 * b2i + 1][0] : pkm1[2 * b2i][0];
          ow1 = h ? pkm1[2 * b2i + 1][1] : pkm1[2 * b2i][1];
          sd0 = h ? pkm1[2 * b2i][0] : pkm1[2 * b2i + 1][0];
          sd1 = h ? pkm1[2 * b2i][1] : pkm1[2 * b2i + 1][1];
        }
        unsigned rv0 = (unsigned)__shfl_xor((int)sd0, 32);
        unsigned rv1 = (unsigned)__shfl_xor((int)sd1, 32);
        uint4v fw = {h ? rv0 : ow0, h ? rv1 : ow1, h ? ow0 : rv0, h ? ow1 : rv1};
        sh8 pf = __builtin_bit_cast(sh8, fw);
        const int b2 = x * 2 + b2i;
        __builtin_amdgcn_s_setprio(1);
#pragma unroll
        for (int ct = 0; ct < 4; ct++) {
          sh8 vf = *(const sh8*)(vbuf + ct * 4096 + voff[b2]);
          o[ct] = __builtin_amdgcn_mfma_f32_32x32x16_bf16(vf, pf, o[ct], 0, 0, 0);
        }
        __builtin_amdgcn_s_setprio(0);
      }
    }
    // drain next-tile DMA (it had the whole compute phase to land), publish
    asm volatile("s_waitcnt vmcnt(0)" ::: "memory");
    __builtin_amdgcn_s_barrier();
    buf ^= 1;
  }
#undef STAGE

  // epilogue: store unnormalized partial O (bf16) + m/l
  u16* op = Opart + (((size_t)kvq * BB + b) * NTOK + qb0 + w * 32 + l31) * CAv;
#pragma unroll
  for (int ct = 0; ct < 4; ct++)
#pragma unroll
    for (int rq = 0; rq < 4; rq++) {
      uint2v d = {pk2(o[ct][4 * rq + 0], o[ct][4 * rq + 1]),
                  pk2(o[ct][4 * rq + 2], o[ct][4 * rq + 3])};
      *(uint2v*)(op + ct * 32 + rq * 8 + h * 4) = d;
    }
  if (h == 0) {
    size_t mi = ((size_t)kvq * BB + b) * NTOK + qb0 + w * 32 + l31;
    Mpart[mi] = m;
    Lpart[mi] = lsum;
  }
}

// ---------------- output projection + 5-way kv merge + residual ----------------
__global__ __launch_bounds__(512) void outproj(const float* __restrict__ met,
                                               const float* __restrict__ woT,
                                               const float* __restrict__ bo,
                                               const u16* __restrict__ Opart,
                                               const float* __restrict__ Mpart,
                                               const float* __restrict__ Lpart,
                                               float* __restrict__ out) {
  const int bs = (blockIdx.x & 7) * 50 + (blockIdx.x >> 3);
  const int b = bs / 100;
  const int tokb = (bs % 100) * 64;
  const int tok = threadIdx.x & 63;
  const int chg = __builtin_amdgcn_readfirstlane(threadIdx.x >> 6);  // 0..7
  const size_t n = (size_t)b * NTOK + tokb + tok;
  const size_t PSTR = (size_t)BB * NTOK;
  // merge weights for the five kv-fifths
  float mq[KVSPLIT], lq[KVSPLIT];
#pragma unroll
  for (int i = 0; i < KVSPLIT; i++) {
    mq[i] = Mpart[i * PSTR + n];
    lq[i] = Lpart[i * PSTR + n];
  }
  float M = mq[0];
#pragma unroll
  for (int i = 1; i < KVSPLIT; i++) M = fmaxf(M, mq[i]);
  float a[KVSPLIT];
  float L = 0.f;
#pragma unroll
  for (int i = 0; i < KVSPLIT; i++) {
    a[i] = __builtin_exp2f(mq[i] - M);
    L += lq[i] * a[i];
  }
  float rL = 1.f / L;
#pragma unroll
  for (int i = 0; i < KVSPLIT; i++) a[i] *= rL;
  const u16* ob[KVSPLIT];
#pragma unroll
  for (int i = 0; i < KVSPLIT; i++) ob[i] = Opart + (i * PSTR + n) * CAv;
  float acc[32];
#pragma unroll
  for (int j = 0; j < 32; j++) acc[j] = 0.f;
#pragma unroll 2
  for (int c8 = 0; c8 < 16; c8++) {
    sh8 v0 = *(const sh8*)(ob[0] + c8 * 8);
    sh8 v1 = *(const sh8*)(ob[1] + c8 * 8);
    sh8 v2 = *(const sh8*)(ob[2] + c8 * 8);
    sh8 v3 = *(const sh8*)(ob[3] + c8 * 8);
    sh8 v4 = *(const sh8*)(ob[4] + c8 * 8);
#pragma unroll
    for (int e = 0; e < 8; e++) {
      float ov = bf2f((u16)v0[e]) * a[0] + bf2f((u16)v1[e]) * a[1] +
                 bf2f((u16)v2[e]) * a[2] + bf2f((u16)v3[e]) * a[3] +
                 bf2f((u16)v4[e]) * a[4];
      const float* wt = woT + (c8 * 8 + e) * CMv + chg * 32;
#pragma unroll
      for (int j = 0; j < 32; j++) acc[j] = fmaf(wt[j], ov, acc[j]);
    }
  }
#pragma unroll
  for (int j = 0; j < 32; j++) {
    int ch = chg * 32 + j;
    size_t idx = ((size_t)b * CMv + ch) * NTOK + tokb + tok;
    out[idx] = met[idx] + acc[j] + bo[ch];
  }
}

extern "C" void kernel_launch(void* const* d_in, const int* in_sizes, int n_in,
                              void* d_out, int out_size, void* d_ws, size_t ws_size,
                              hipStream_t stream) {
  const float* met = (const float*)d_in[0];
  const float* ter = (const float*)d_in[1];
  const float* wq = (const float*)d_in[2];
  const float* bq = (const float*)d_in[3];
  const float* wk = (const float*)d_in[4];
  const float* bk = (const float*)d_in[5];
  const float* wv = (const float*)d_in[6];
  const float* bv = (const float*)d_in[7];
  const float* wo = (const float*)d_in[8];
  const float* bo = (const float*)d_in[9];
  float* out = (float*)d_out;

  u16* Qtm = (u16*)d_ws;                                  // B*N*CA bf16
  u16* Ktm = Qtm + (size_t)BB * NTOK * CAv;               // B*N*CA bf16
  u16* Vcm = Ktm + (size_t)BB * NTOK * CAv;               // B*CA*N bf16
  u16* Opart = Vcm + (size_t)BB * NTOK * CAv;             // 5*B*N*CA bf16
  float* Mpart = (float*)(Opart + (size_t)KVSPLIT * BB * NTOK * CAv);  // 5*B*N
  float* Lpart = Mpart + (size_t)KVSPLIT * BB * NTOK;
  float* wqT = Lpart + (size_t)KVSPLIT * BB * NTOK;
  float* wkT = wqT + 256 * 128;
  float* wvT = wkT + 64 * 128;
  float* woT = wvT + 64 * 128;

  prepw<<<dim3(32), dim3(256), 0, stream>>>(wq, wk, wv, wo, wqT, wkT, wvT, woT);
  qproj<<<dim3(400), dim3(256), 0, stream>>>(met, wqT, bq, Qtm);
  kvproj<<<dim3(400), dim3(512), 0, stream>>>(ter, wkT, bk, wvT, bv, Ktm, Vcm);
  attn<<<dim3(500), dim3(512), 0, stream>>>(Qtm, Ktm, Vcm, Opart, Mpart, Lpart);
  outproj<<<dim3(400), dim3(512), 0, stream>>>(met, woT, bo, Opart, Mpart, Lpart, out);
}